// Round 4
// baseline (1187.778 us; speedup 1.0000x reference)
//
#include <hip/hip_runtime.h>
#include <math.h>

#define Bsz 64
#define Tt  32
#define Dv  2048
#define Hd  1024
#define G3  3072
#define Vv  20000
#define ML  3

typedef __attribute__((ext_vector_type(8))) short bf16x8;
typedef __attribute__((ext_vector_type(4))) float f32x4;
#define MFMA(a,b,c) __builtin_amdgcn_mfma_f32_16x16x32_bf16(a,b,c,0,0,0)

__device__ __forceinline__ short f2bf(float f) {
    union { float f; unsigned u; } v; v.f = f;
    unsigned r = v.u + 0x7fffu + ((v.u >> 16) & 1u);
    return (short)(r >> 16);
}
__device__ __forceinline__ float bf2f(short s) {
    union { unsigned u; float f; } v; v.u = ((unsigned)(unsigned short)s) << 16;
    return v.f;
}

// ---------------------------------------------------------------------------
// fp32 -> bf16 conversion, 8 elems/thread, optional row slicing (for W_ih2).
// ---------------------------------------------------------------------------
__global__ __launch_bounds__(256)
void cvt_f32_bf16(const float* __restrict__ src, short* __restrict__ dst,
                  long total8, long cols8, int src_ld, int dst_ld)
{
    long i = (long)blockIdx.x * 256 + threadIdx.x;
    if (i >= total8) return;
    long r = i / cols8; long c = i - r * cols8;
    const float* s = src + r * (long)src_ld + c * 8;
    float4 x = *(const float4*)s;
    float4 y = *(const float4*)(s + 4);
    bf16x8 o;
    o[0]=f2bf(x.x); o[1]=f2bf(x.y); o[2]=f2bf(x.z); o[3]=f2bf(x.w);
    o[4]=f2bf(y.x); o[5]=f2bf(y.y); o[6]=f2bf(y.z); o[7]=f2bf(y.w);
    *(bf16x8*)(dst + r * (long)dst_ld + c * 8) = o;
}

// ---------------------------------------------------------------------------
// Big MFMA GEMM (unchanged): C[M,N] = A*W^T + bias, 128x128 tile.
// ---------------------------------------------------------------------------
__global__ __launch_bounds__(256)
void gemm_mfma_128(const short* __restrict__ A, int lda,
                   const short* __restrict__ W, int ldw,
                   const float* __restrict__ bias,
                   float* __restrict__ C, int ldc, int K)
{
    __shared__ __align__(16) short As[128 * 40];
    __shared__ __align__(16) short Bs[128 * 40];
    const int tid = threadIdx.x;
    const int w = tid >> 6, l = tid & 63;
    const int wm = w >> 1, wn = w & 1;
    const int lr = l & 15, lg = l >> 4;
    const int m0 = blockIdx.y * 128, n0 = blockIdx.x * 128;
    const int sm = tid >> 2;
    const int skg = tid & 3;

    f32x4 acc[4][4] = {};

    for (int k0 = 0; k0 < K; k0 += 32) {
        #pragma unroll
        for (int i = 0; i < 2; ++i) {
            const int m = i * 64 + sm;
            bf16x8 av = *(const bf16x8*)(A + (size_t)(m0 + m) * lda + k0 + skg * 8);
            bf16x8 wv = *(const bf16x8*)(W + (size_t)(n0 + m) * ldw + k0 + skg * 8);
            *(bf16x8*)(As + m * 40 + skg * 8) = av;
            *(bf16x8*)(Bs + m * 40 + skg * 8) = wv;
        }
        __syncthreads();
        bf16x8 af[4], bfr[4];
        #pragma unroll
        for (int mt = 0; mt < 4; ++mt) {
            const int m = wm * 64 + mt * 16 + lr;
            const int n = wn * 64 + mt * 16 + lr;
            af[mt]  = *(const bf16x8*)(As + m * 40 + lg * 8);
            bfr[mt] = *(const bf16x8*)(Bs + n * 40 + lg * 8);
        }
        #pragma unroll
        for (int mt = 0; mt < 4; ++mt)
            #pragma unroll
            for (int nt = 0; nt < 4; ++nt)
                acc[mt][nt] = MFMA(af[mt], bfr[nt], acc[mt][nt]);
        __syncthreads();
    }

    #pragma unroll
    for (int mt = 0; mt < 4; ++mt)
        #pragma unroll
        for (int nt = 0; nt < 4; ++nt)
            #pragma unroll
            for (int v = 0; v < 4; ++v) {
                const int m = m0 + wm * 64 + mt * 16 + lg * 4 + v;
                const int n = n0 + wn * 64 + nt * 16 + lr;
                C[(size_t)m * ldc + n] = acc[mt][nt][v] + bias[n];
            }
}

// ---------------------------------------------------------------------------
// Persistent GRU scan v2: W slice in REGISTERS (zero LDS in k-loop).
// 64 blocks x 256 thr (4 waves). Block owns 16 gate-columns j0=blk*16 for
// all 3 gates. Wave w owns K-quarter [w*256, w*256+256): holds 24 B-frags
// (3 gates x 8 k-slices) in VGPRs for the whole launch. Per step: all 32
// A-frags (h) + epilogue operands loaded in ONE latency hop, 96 MFMA, then
// K-partials exchanged via 48KB LDS; wave w does the epilogue for batches
// [w*16, w*16+16). Grid sync: 8x8 tree barrier (leaf by blk&7, root) with
// release-epoch broadcast + acquire spin (agent scope -> cross-XCD coherent).
// xp row for (batch b, step s) = b*xp_rs + s*xp_ts (both 0 -> broadcast bias).
// ---------------------------------------------------------------------------
__global__ __launch_bounds__(256, 1)
void gru_scan(const float* __restrict__ xp, int xp_rs, int xp_ts,
              const short* __restrict__ Whh,   // bf16 [3072][1024]
              const float* __restrict__ b_hh,
              short* __restrict__ hb0, short* __restrict__ hb1, int p0,
              short* __restrict__ out_seq,     // bf16 (T*64,1024) or null
              int T, unsigned int* __restrict__ bar)
{
    __shared__ __align__(16) float xch[4][4][3][256];  // [src_w][mt][g][lane*4] 48KB
    const int tid = threadIdx.x;
    const int w  = tid >> 6;          // K-quarter, also epilogue mt
    const int l  = tid & 63;
    const int lr = l & 15, lg = l >> 4;
    const int j0 = blockIdx.x * 16;
    const int j  = j0 + lr;

    // ---- B fragments: 3 gates x 8 k-slices, resident in VGPRs ----
    bf16x8 Bf[3][8];
    #pragma unroll
    for (int g = 0; g < 3; ++g)
        #pragma unroll
        for (int ks = 0; ks < 8; ++ks)
            Bf[g][ks] = *(const bf16x8*)(Whh + (size_t)(g * Hd + j) * Hd
                                         + w * 256 + ks * 32 + lg * 8);

    const float bh0 = b_hh[j], bh1 = b_hh[Hd + j], bh2 = b_hh[2 * Hd + j];

    for (int s = 0; s < T; ++s) {
        const short* hin  = ((p0 + s) & 1) ? hb1 : hb0;
        short*       hout = ((p0 + s) & 1) ? hb0 : hb1;

        // ---- one-hop load phase: 32 A-frags + epilogue operands ----
        bf16x8 A[4][8];
        #pragma unroll
        for (int mt = 0; mt < 4; ++mt)
            #pragma unroll
            for (int ks = 0; ks < 8; ++ks)
                A[mt][ks] = *(const bf16x8*)(hin + (size_t)(mt * 16 + lr) * Hd
                                             + w * 256 + ks * 32 + lg * 8);
        float xr[4], xz[4], xn[4], hp[4];
        #pragma unroll
        for (int v = 0; v < 4; ++v) {
            const int b = w * 16 + lg * 4 + v;
            const float* xrow = xp + (size_t)(b * xp_rs + s * xp_ts) * G3;
            xr[v] = xrow[j];
            xz[v] = xrow[Hd + j];
            xn[v] = xrow[2 * Hd + j];
            hp[v] = bf2f(hin[(size_t)b * Hd + j]);
        }

        // ---- 96 MFMA: K-quarter partials for all 4 m-tiles, 3 gates ----
        f32x4 acc[4][3] = {};
        #pragma unroll
        for (int ks = 0; ks < 8; ++ks)
            #pragma unroll
            for (int mt = 0; mt < 4; ++mt)
                #pragma unroll
                for (int g = 0; g < 3; ++g)
                    acc[mt][g] = MFMA(A[mt][ks], Bf[g][ks], acc[mt][g]);

        // ---- cross-wave K reduction via LDS ----
        #pragma unroll
        for (int mt = 0; mt < 4; ++mt)
            #pragma unroll
            for (int g = 0; g < 3; ++g)
                *(f32x4*)&xch[w][mt][g][l * 4] = acc[mt][g];
        __syncthreads();
        f32x4 tot[3];
        #pragma unroll
        for (int g = 0; g < 3; ++g) {
            f32x4 t0 = *(const f32x4*)&xch[0][w][g][l * 4];
            f32x4 t1 = *(const f32x4*)&xch[1][w][g][l * 4];
            f32x4 t2 = *(const f32x4*)&xch[2][w][g][l * 4];
            f32x4 t3 = *(const f32x4*)&xch[3][w][g][l * 4];
            tot[g] = (t0 + t1) + (t2 + t3);
        }

        // ---- gates + h update (wave w handles batches w*16..w*16+15) ----
        #pragma unroll
        for (int v = 0; v < 4; ++v) {
            const int b = w * 16 + lg * 4 + v;
            const float rg = 1.f / (1.f + __expf(-(xr[v] + tot[0][v] + bh0)));
            const float zg = 1.f / (1.f + __expf(-(xz[v] + tot[1][v] + bh1)));
            const float ng = tanhf(xn[v] + rg * (tot[2][v] + bh2));
            const float hv = (1.f - zg) * ng + zg * hp[v];
            const short hb = f2bf(hv);
            hout[(size_t)b * Hd + j] = hb;
            if (out_seq) out_seq[((size_t)s * 64 + b) * Hd + j] = hb;
        }

        // ---- tree grid barrier (skip after last step) ----
        if (s != T - 1) {
            __syncthreads();   // xch reads done (WAR) + h stores issued
            if (tid == 0) {
                const unsigned target = (unsigned)(s + 1);
                unsigned who = __hip_atomic_fetch_add(&bar[(blockIdx.x & 7) * 16], 1u,
                                                      __ATOMIC_ACQ_REL,
                                                      __HIP_MEMORY_SCOPE_AGENT);
                if (who == target * 8u - 1u) {
                    unsigned wr = __hip_atomic_fetch_add(&bar[128], 1u,
                                                         __ATOMIC_ACQ_REL,
                                                         __HIP_MEMORY_SCOPE_AGENT);
                    if (wr == target * 8u - 1u)
                        __hip_atomic_store(&bar[192], target, __ATOMIC_RELEASE,
                                           __HIP_MEMORY_SCOPE_AGENT);
                }
                while (__hip_atomic_load(&bar[192], __ATOMIC_ACQUIRE,
                                         __HIP_MEMORY_SCOPE_AGENT) < target) {
                    __builtin_amdgcn_s_sleep(2);
                }
            }
            __syncthreads();
        }
    }
}

// ---------------------------------------------------------------------------
// Skinny MFMA GEMM (unchanged): C[64,N]f32 = A[64,1024]bf16 * W[N,1024]^T + b.
// ---------------------------------------------------------------------------
template<bool WF32>
__global__ __launch_bounds__(64)
void skinny_mfma(const short* __restrict__ A,
                 const void* __restrict__ Wp,
                 const float* __restrict__ bias,
                 float* __restrict__ C, int N)
{
    const int l = threadIdx.x;
    const int lr = l & 15, lg = l >> 4;
    const int n0 = blockIdx.x * 16;
    const size_t wrow = (size_t)(n0 + lr) * Hd + lg * 8;
    const short* pa = A + (size_t)lr * Hd + lg * 8;

    f32x4 acc0 = {}, acc1 = {}, acc2 = {}, acc3 = {};

    auto ldA = [&](int mtt, int ks) {
        return *(const bf16x8*)(pa + mtt * 16 * Hd + ks * 32);
    };
    auto ldW = [&](int ks) -> bf16x8 {
        if constexpr (WF32) {
            const float* p = (const float*)Wp + wrow + ks * 32;
            float4 x = *(const float4*)p;
            float4 y = *(const float4*)(p + 4);
            bf16x8 r;
            r[0]=f2bf(x.x); r[1]=f2bf(x.y); r[2]=f2bf(x.z); r[3]=f2bf(x.w);
            r[4]=f2bf(y.x); r[5]=f2bf(y.y); r[6]=f2bf(y.z); r[7]=f2bf(y.w);
            return r;
        } else {
            return *(const bf16x8*)((const short*)Wp + wrow + ks * 32);
        }
    };

    bf16x8 a00=ldA(0,0), a01=ldA(1,0), a02=ldA(2,0), a03=ldA(3,0), w0=ldW(0);
    bf16x8 a10=ldA(0,1), a11=ldA(1,1), a12=ldA(2,1), a13=ldA(3,1), w1=ldW(1);

    #pragma unroll
    for (int ks = 0; ks < 32; ks += 2) {
        const int k2 = (ks + 2) & 31;
        const int k3 = (ks + 3) & 31;
        acc0 = MFMA(a00, w0, acc0);
        acc1 = MFMA(a01, w0, acc1);
        acc2 = MFMA(a02, w0, acc2);
        acc3 = MFMA(a03, w0, acc3);
        a00=ldA(0,k2); a01=ldA(1,k2); a02=ldA(2,k2); a03=ldA(3,k2); w0=ldW(k2);
        acc0 = MFMA(a10, w1, acc0);
        acc1 = MFMA(a11, w1, acc1);
        acc2 = MFMA(a12, w1, acc2);
        acc3 = MFMA(a13, w1, acc3);
        a10=ldA(0,k3); a11=ldA(1,k3); a12=ldA(2,k3); a13=ldA(3,k3); w1=ldW(k3);
    }

    const float bn = bias[n0 + lr];
    #pragma unroll
    for (int v = 0; v < 4; ++v) {
        C[(size_t)( 0 + lg * 4 + v) * N + n0 + lr] = acc0[v] + bn;
        C[(size_t)(16 + lg * 4 + v) * N + n0 + lr] = acc1[v] + bn;
        C[(size_t)(32 + lg * 4 + v) * N + n0 + lr] = acc2[v] + bn;
        C[(size_t)(48 + lg * 4 + v) * N + n0 + lr] = acc3[v] + bn;
    }
}

// ---------------------------------------------------------------------------
// Row log-softmax over V=20000, out[b][step][v].
// ---------------------------------------------------------------------------
__global__ __launch_bounds__(256)
void log_softmax_k(const float* __restrict__ logits, float* __restrict__ out, int step)
{
    __shared__ float red[4];
    const int b   = blockIdx.x;
    const int tid = threadIdx.x;
    const float* row = logits + (size_t)b * Vv;

    float m = -1e30f;
    for (int v = tid; v < Vv; v += 256) m = fmaxf(m, row[v]);
    #pragma unroll
    for (int off = 32; off > 0; off >>= 1) m = fmaxf(m, __shfl_down(m, off, 64));
    if ((tid & 63) == 0) red[tid >> 6] = m;
    __syncthreads();
    m = fmaxf(fmaxf(red[0], red[1]), fmaxf(red[2], red[3]));
    __syncthreads();

    float s = 0.f;
    for (int v = tid; v < Vv; v += 256) s += expf(row[v] - m);
    #pragma unroll
    for (int off = 32; off > 0; off >>= 1) s += __shfl_down(s, off, 64);
    if ((tid & 63) == 0) red[tid >> 6] = s;
    __syncthreads();
    s = red[0] + red[1] + red[2] + red[3];
    const float lse = m + logf(s);

    float* orow = out + ((size_t)b * ML + step) * Vv;
    for (int v = tid; v < Vv; v += 256) orow[v] = row[v] - lse;
}

// ---------------------------------------------------------------------------
extern "C" void kernel_launch(void* const* d_in, const int* in_sizes, int n_in,
                              void* d_out, int out_size, void* d_ws, size_t ws_size,
                              hipStream_t stream)
{
    (void)in_sizes; (void)n_in; (void)out_size; (void)ws_size;
    const float* vid   = (const float*)d_in[0];
    const float* W_ih1 = (const float*)d_in[1];
    const float* W_hh1 = (const float*)d_in[2];
    const float* b_ih1 = (const float*)d_in[3];
    const float* b_hh1 = (const float*)d_in[4];
    const float* W_ih2 = (const float*)d_in[5];   // (3072,1536); cols 0..1023 used
    const float* W_hh2 = (const float*)d_in[6];
    const float* b_ih2 = (const float*)d_in[7];
    const float* b_hh2 = (const float*)d_in[8];
    const float* W_obj = (const float*)d_in[9];
    const float* b_obj = (const float*)d_in[10];
    const float* W_rel = (const float*)d_in[11];
    const float* b_rel = (const float*)d_in[12];
    float* out = (float*)d_out;

    // workspace carve-up
    char* p = (char*)d_ws;
    short* vid_bf   = (short*)p; p += (size_t)2048 * Dv * 2;        // 8.0 MB
    short* Wih1_bf  = (short*)p; p += (size_t)G3 * Dv * 2;          // 12.6 MB
    short* Whh1_bf  = (short*)p; p += (size_t)G3 * Hd * 2;          // 6.3 MB
    short* Wih2c_bf = (short*)p; p += (size_t)G3 * Hd * 2;          // 6.3 MB
    short* Whh2_bf  = (short*)p; p += (size_t)G3 * Hd * 2;          // 6.3 MB
    short* out1_bf  = (short*)p; p += (size_t)2048 * Hd * 2;        // 4.2 MB
    // --- zero zone (one memset): h double-buffers + barrier area ---
    char* zz = p;
    short* h1a = (short*)p; p += (size_t)64 * Hd * 2;
    short* h1b = (short*)p; p += (size_t)64 * Hd * 2;
    short* h2a = (short*)p; p += (size_t)64 * Hd * 2;
    short* h2b = (short*)p; p += (size_t)64 * Hd * 2;
    unsigned int* bar = (unsigned int*)p; p += 2 * 1024;            // 2 sets x 256 uints
    size_t zz_bytes = (size_t)(p - zz);
    float* xp1    = (float*)p; p += (size_t)2048 * G3 * 4;          // 25.2 MB (also xp2)
    float* xp2t   = (float*)p; p += (size_t)64 * G3 * 4;
    float* logits = (float*)p; p += (size_t)64 * Vv * 4;

    hipMemsetAsync(zz, 0, zz_bytes, stream);

    // conversions to bf16
    {
        long t8;
        t8 = (long)2048 * Dv / 8;
        cvt_f32_bf16<<<(t8 + 255) / 256, 256, 0, stream>>>(vid, vid_bf, t8, t8, 0, 0);
        t8 = (long)G3 * Dv / 8;
        cvt_f32_bf16<<<(t8 + 255) / 256, 256, 0, stream>>>(W_ih1, Wih1_bf, t8, t8, 0, 0);
        t8 = (long)G3 * Hd / 8;
        cvt_f32_bf16<<<(t8 + 255) / 256, 256, 0, stream>>>(W_hh1, Whh1_bf, t8, t8, 0, 0);
        cvt_f32_bf16<<<(t8 + 255) / 256, 256, 0, stream>>>(W_hh2, Whh2_bf, t8, t8, 0, 0);
        cvt_f32_bf16<<<(t8 + 255) / 256, 256, 0, stream>>>(W_ih2, Wih2c_bf, t8, Hd / 8,
                                                           Hd + 512, Hd);
    }

    // Phase 1: xp1 = vid @ W_ih1^T + b_ih1   (M=2048, N=3072, K=2048)
    gemm_mfma_128<<<dim3(G3 / 128, 2048 / 128), 256, 0, stream>>>(
        vid_bf, Dv, Wih1_bf, Dv, b_ih1, xp1, G3, Dv);

    // Phase 2: layer-1 scan, ONE launch (xp row = b*32 + s), writes out1
    gru_scan<<<64, 256, 0, stream>>>(xp1, Tt, 1, Whh1_bf, b_hh1,
                                     h1a, h1b, 0, out1_bf, Tt, bar + 0);
    int p1 = 0;  // (0 + 32) & 1 == 0 -> final h1 in h1a

    // Phase 3: xp2 = out1 @ W_ih2[:, :H]^T + b_ih2  (M=2048, N=3072, K=1024)
    float* xp2 = xp1;
    gemm_mfma_128<<<dim3(G3 / 128, 2048 / 128), 256, 0, stream>>>(
        out1_bf, Hd, Wih2c_bf, Hd, b_ih2, xp2, G3, Hd);

    // Phase 4: layer-2 scan, ONE launch (xp row = s*64 + b)
    gru_scan<<<64, 256, 0, stream>>>(xp2, 1, 64, Whh2_bf, b_hh2,
                                     h2a, h2b, 0, nullptr, Tt, bar + 256);
    int p2 = 0;

    // Phase 5: decode (gru_scan with T=1; barrier not executed)
    for (int i = 0; i < ML; ++i) {
        gru_scan<<<64, 256, 0, stream>>>(b_ih1, 0, 0, Whh1_bf, b_hh1,
                                         h1a, h1b, p1, nullptr, 1, bar);
        p1 ^= 1;
        short* h1cur = p1 ? h1b : h1a;
        skinny_mfma<false><<<G3 / 16, 64, 0, stream>>>(h1cur, (const void*)Wih2c_bf,
                                                       b_ih2, xp2t, G3);
        gru_scan<<<64, 256, 0, stream>>>(xp2t, 1, 0, Whh2_bf, b_hh2,
                                         h2a, h2b, p2, nullptr, 1, bar);
        p2 ^= 1;
        short* h2cur = p2 ? h2b : h2a;
        const float* Wo = (i == 1) ? W_rel : W_obj;
        const float* bo = (i == 1) ? b_rel : b_obj;
        skinny_mfma<true><<<Vv / 16, 64, 0, stream>>>(h2cur, (const void*)Wo, bo,
                                                      logits, Vv);
        log_softmax_k<<<64, 256, 0, stream>>>(logits, out, i);
    }
}

// Round 5
// 1087.055 us; speedup vs baseline: 1.0927x; 1.0927x over previous
//
#include <hip/hip_runtime.h>
#include <math.h>

#define Bsz 64
#define Tt  32
#define Dv  2048
#define Hd  1024
#define G3  3072
#define Vv  20000
#define ML  3

typedef __attribute__((ext_vector_type(8))) short bf16x8;
typedef __attribute__((ext_vector_type(4))) float f32x4;
#define MFMA(a,b,c) __builtin_amdgcn_mfma_f32_16x16x32_bf16(a,b,c,0,0,0)

__device__ __forceinline__ short f2bf(float f) {
    union { float f; unsigned u; } v; v.f = f;
    unsigned r = v.u + 0x7fffu + ((v.u >> 16) & 1u);
    return (short)(r >> 16);
}
__device__ __forceinline__ float bf2f(short s) {
    union { unsigned u; float f; } v; v.u = ((unsigned)(unsigned short)s) << 16;
    return v.f;
}

// ---------------------------------------------------------------------------
// fp32 -> bf16 conversion, 8 elems/thread, optional row slicing (for W_ih2).
// ---------------------------------------------------------------------------
__global__ __launch_bounds__(256)
void cvt_f32_bf16(const float* __restrict__ src, short* __restrict__ dst,
                  long total8, long cols8, int src_ld, int dst_ld)
{
    long i = (long)blockIdx.x * 256 + threadIdx.x;
    if (i >= total8) return;
    long r = i / cols8; long c = i - r * cols8;
    const float* s = src + r * (long)src_ld + c * 8;
    float4 x = *(const float4*)s;
    float4 y = *(const float4*)(s + 4);
    bf16x8 o;
    o[0]=f2bf(x.x); o[1]=f2bf(x.y); o[2]=f2bf(x.z); o[3]=f2bf(x.w);
    o[4]=f2bf(y.x); o[5]=f2bf(y.y); o[6]=f2bf(y.z); o[7]=f2bf(y.w);
    *(bf16x8*)(dst + r * (long)dst_ld + c * 8) = o;
}

// ---------------------------------------------------------------------------
// Big MFMA GEMM (unchanged): C[M,N] = A*W^T + bias, 128x128 tile.
// ---------------------------------------------------------------------------
__global__ __launch_bounds__(256)
void gemm_mfma_128(const short* __restrict__ A, int lda,
                   const short* __restrict__ W, int ldw,
                   const float* __restrict__ bias,
                   float* __restrict__ C, int ldc, int K)
{
    __shared__ __align__(16) short As[128 * 40];
    __shared__ __align__(16) short Bs[128 * 40];
    const int tid = threadIdx.x;
    const int w = tid >> 6, l = tid & 63;
    const int wm = w >> 1, wn = w & 1;
    const int lr = l & 15, lg = l >> 4;
    const int m0 = blockIdx.y * 128, n0 = blockIdx.x * 128;
    const int sm = tid >> 2;
    const int skg = tid & 3;

    f32x4 acc[4][4] = {};

    for (int k0 = 0; k0 < K; k0 += 32) {
        #pragma unroll
        for (int i = 0; i < 2; ++i) {
            const int m = i * 64 + sm;
            bf16x8 av = *(const bf16x8*)(A + (size_t)(m0 + m) * lda + k0 + skg * 8);
            bf16x8 wv = *(const bf16x8*)(W + (size_t)(n0 + m) * ldw + k0 + skg * 8);
            *(bf16x8*)(As + m * 40 + skg * 8) = av;
            *(bf16x8*)(Bs + m * 40 + skg * 8) = wv;
        }
        __syncthreads();
        bf16x8 af[4], bfr[4];
        #pragma unroll
        for (int mt = 0; mt < 4; ++mt) {
            const int m = wm * 64 + mt * 16 + lr;
            const int n = wn * 64 + mt * 16 + lr;
            af[mt]  = *(const bf16x8*)(As + m * 40 + lg * 8);
            bfr[mt] = *(const bf16x8*)(Bs + n * 40 + lg * 8);
        }
        #pragma unroll
        for (int mt = 0; mt < 4; ++mt)
            #pragma unroll
            for (int nt = 0; nt < 4; ++nt)
                acc[mt][nt] = MFMA(af[mt], bfr[nt], acc[mt][nt]);
        __syncthreads();
    }

    #pragma unroll
    for (int mt = 0; mt < 4; ++mt)
        #pragma unroll
        for (int nt = 0; nt < 4; ++nt)
            #pragma unroll
            for (int v = 0; v < 4; ++v) {
                const int m = m0 + wm * 64 + mt * 16 + lg * 4 + v;
                const int n = n0 + wn * 64 + nt * 16 + lr;
                C[(size_t)m * ldc + n] = acc[mt][nt][v] + bias[n];
            }
}

// ---------------------------------------------------------------------------
// Persistent GRU scan v3.
//  - W slice pinned in VGPRs via asm keep-alive (no remat, no reload).
//  - h carried in f32 registers across steps (epilogue owner == next consumer).
//  - xp for step s+1 prefetched BEFORE the barrier.
//  - Grid barrier: relaxed leaf/root RMWs + relaxed flag spin (no cache
//    maintenance per poll); ONE release fence (wbl2) before leaf add, ONE
//    acquire fence (inv) after flag observed. __syncthreads() drains vmcnt
//    so all waves' h-stores are in L2 before the wbl2.
// 64 blocks x 256 thr; block owns 16 gate-cols j0=blk*16 (all 3 gates);
// wave w owns K-quarter; K-partials exchanged via 48KB LDS (conflict-free).
// ---------------------------------------------------------------------------
__global__ __launch_bounds__(256, 1)
void gru_scan(const float* __restrict__ xp, int xp_rs, int xp_ts,
              const short* __restrict__ Whh,   // bf16 [3072][1024]
              const float* __restrict__ b_hh,
              short* __restrict__ hb0, short* __restrict__ hb1, int p0,
              short* __restrict__ out_seq,     // bf16 (T*64,1024) or null
              int T, unsigned int* __restrict__ bar)
{
    __shared__ __align__(16) float xch[4][4][3][256];  // [src_w][mt][g][lane*4] 48KB
    const int tid = threadIdx.x;
    const int w  = tid >> 6;          // K-quarter, also epilogue batch-tile
    const int l  = tid & 63;
    const int lr = l & 15, lg = l >> 4;
    const int j0 = blockIdx.x * 16;
    const int j  = j0 + lr;

    // ---- B fragments: 3 gates x 8 k-slices, PINNED in VGPRs ----
    bf16x8 Bf[3][8];
    #pragma unroll
    for (int g = 0; g < 3; ++g)
        #pragma unroll
        for (int ks = 0; ks < 8; ++ks) {
            Bf[g][ks] = *(const bf16x8*)(Whh + (size_t)(g * Hd + j) * Hd
                                         + w * 256 + ks * 32 + lg * 8);
            asm volatile("" : "+v"(Bf[g][ks]));   // opaque: no remat/sink
        }

    const float bh0 = b_hh[j], bh1 = b_hh[Hd + j], bh2 = b_hh[2 * Hd + j];

    // ---- h carried in f32 regs; initial load once ----
    float hp[4];
    {
        const short* hin0 = (p0 & 1) ? hb1 : hb0;
        #pragma unroll
        for (int v = 0; v < 4; ++v)
            hp[v] = bf2f(hin0[(size_t)(w * 16 + lg * 4 + v) * Hd + j]);
    }
    // ---- prefetch xp for step 0 ----
    float xr[4], xz[4], xn[4];
    #pragma unroll
    for (int v = 0; v < 4; ++v) {
        const int b = w * 16 + lg * 4 + v;
        const float* xrow = xp + (size_t)(b * xp_rs) * G3;
        xr[v] = xrow[j]; xz[v] = xrow[Hd + j]; xn[v] = xrow[2 * Hd + j];
    }

    for (int s = 0; s < T; ++s) {
        const short* hin  = ((p0 + s) & 1) ? hb1 : hb0;
        short*       hout = ((p0 + s) & 1) ? hb0 : hb1;

        // ---- one-hop load: 32 A-frags (whole h for this K-quarter) ----
        bf16x8 A[4][8];
        #pragma unroll
        for (int mt = 0; mt < 4; ++mt)
            #pragma unroll
            for (int ks = 0; ks < 8; ++ks)
                A[mt][ks] = *(const bf16x8*)(hin + (size_t)(mt * 16 + lr) * Hd
                                             + w * 256 + ks * 32 + lg * 8);

        // ---- 96 MFMA: K-quarter partials, 4 m-tiles x 3 gates ----
        f32x4 acc[4][3] = {};
        #pragma unroll
        for (int ks = 0; ks < 8; ++ks)
            #pragma unroll
            for (int mt = 0; mt < 4; ++mt)
                #pragma unroll
                for (int g = 0; g < 3; ++g)
                    acc[mt][g] = MFMA(A[mt][ks], Bf[g][ks], acc[mt][g]);

        // ---- cross-wave K reduction via LDS (conflict-free) ----
        #pragma unroll
        for (int mt = 0; mt < 4; ++mt)
            #pragma unroll
            for (int g = 0; g < 3; ++g)
                *(f32x4*)&xch[w][mt][g][l * 4] = acc[mt][g];
        __syncthreads();
        f32x4 tot[3];
        #pragma unroll
        for (int g = 0; g < 3; ++g) {
            f32x4 t0 = *(const f32x4*)&xch[0][w][g][l * 4];
            f32x4 t1 = *(const f32x4*)&xch[1][w][g][l * 4];
            f32x4 t2 = *(const f32x4*)&xch[2][w][g][l * 4];
            f32x4 t3 = *(const f32x4*)&xch[3][w][g][l * 4];
            tot[g] = (t0 + t1) + (t2 + t3);
        }

        // ---- gates + h update (wave w owns batches w*16..w*16+15) ----
        #pragma unroll
        for (int v = 0; v < 4; ++v) {
            const int b = w * 16 + lg * 4 + v;
            const float rg = 1.f / (1.f + __expf(-(xr[v] + tot[0][v] + bh0)));
            const float zg = 1.f / (1.f + __expf(-(xz[v] + tot[1][v] + bh1)));
            const float ng = tanhf(xn[v] + rg * (tot[2][v] + bh2));
            const float hv = (1.f - zg) * ng + zg * hp[v];
            hp[v] = hv;                       // f32 carry for next step
            const short hb = f2bf(hv);
            hout[(size_t)b * Hd + j] = hb;
            if (out_seq) out_seq[((size_t)s * 64 + b) * Hd + j] = hb;
        }

        // ---- barrier (skip after last step) ----
        if (s != T - 1) {
            // prefetch next step's xp while stores drain
            #pragma unroll
            for (int v = 0; v < 4; ++v) {
                const int b = w * 16 + lg * 4 + v;
                const float* xrow = xp + (size_t)(b * xp_rs + (s + 1) * xp_ts) * G3;
                xr[v] = xrow[j]; xz[v] = xrow[Hd + j]; xn[v] = xrow[2 * Hd + j];
            }
            __syncthreads();   // drains vmcnt: all waves' h-stores are in L2
            if (tid == 0) {
                const unsigned target = (unsigned)(s + 1);
                __builtin_amdgcn_fence(__ATOMIC_RELEASE, "agent");   // one wbl2
                unsigned who = __hip_atomic_fetch_add(&bar[(blockIdx.x & 7) * 32],
                                                      1u, __ATOMIC_RELAXED,
                                                      __HIP_MEMORY_SCOPE_AGENT);
                if (who == target * 8u - 1u) {
                    unsigned wr = __hip_atomic_fetch_add(&bar[256], 1u,
                                                         __ATOMIC_RELAXED,
                                                         __HIP_MEMORY_SCOPE_AGENT);
                    if (wr == target * 8u - 1u)
                        __hip_atomic_store(&bar[320], target, __ATOMIC_RELAXED,
                                           __HIP_MEMORY_SCOPE_AGENT);
                }
                int spins = 0;
                while (__hip_atomic_load(&bar[320], __ATOMIC_RELAXED,
                                         __HIP_MEMORY_SCOPE_AGENT) < target) {
                    __builtin_amdgcn_s_sleep(2);
                    if (((++spins) & 63) == 0)   // safety: periodic refresh
                        (void)__hip_atomic_load(&bar[320], __ATOMIC_ACQUIRE,
                                                __HIP_MEMORY_SCOPE_AGENT);
                }
                __builtin_amdgcn_fence(__ATOMIC_ACQUIRE, "agent");   // one inv
            }
            __syncthreads();
        }
    }
}

// ---------------------------------------------------------------------------
// Skinny MFMA GEMM (unchanged): C[64,N]f32 = A[64,1024]bf16 * W[N,1024]^T + b.
// ---------------------------------------------------------------------------
template<bool WF32>
__global__ __launch_bounds__(64)
void skinny_mfma(const short* __restrict__ A,
                 const void* __restrict__ Wp,
                 const float* __restrict__ bias,
                 float* __restrict__ C, int N)
{
    const int l = threadIdx.x;
    const int lr = l & 15, lg = l >> 4;
    const int n0 = blockIdx.x * 16;
    const size_t wrow = (size_t)(n0 + lr) * Hd + lg * 8;
    const short* pa = A + (size_t)lr * Hd + lg * 8;

    f32x4 acc0 = {}, acc1 = {}, acc2 = {}, acc3 = {};

    auto ldA = [&](int mtt, int ks) {
        return *(const bf16x8*)(pa + mtt * 16 * Hd + ks * 32);
    };
    auto ldW = [&](int ks) -> bf16x8 {
        if constexpr (WF32) {
            const float* p = (const float*)Wp + wrow + ks * 32;
            float4 x = *(const float4*)p;
            float4 y = *(const float4*)(p + 4);
            bf16x8 r;
            r[0]=f2bf(x.x); r[1]=f2bf(x.y); r[2]=f2bf(x.z); r[3]=f2bf(x.w);
            r[4]=f2bf(y.x); r[5]=f2bf(y.y); r[6]=f2bf(y.z); r[7]=f2bf(y.w);
            return r;
        } else {
            return *(const bf16x8*)((const short*)Wp + wrow + ks * 32);
        }
    };

    bf16x8 a00=ldA(0,0), a01=ldA(1,0), a02=ldA(2,0), a03=ldA(3,0), w0=ldW(0);
    bf16x8 a10=ldA(0,1), a11=ldA(1,1), a12=ldA(2,1), a13=ldA(3,1), w1=ldW(1);

    #pragma unroll
    for (int ks = 0; ks < 32; ks += 2) {
        const int k2 = (ks + 2) & 31;
        const int k3 = (ks + 3) & 31;
        acc0 = MFMA(a00, w0, acc0);
        acc1 = MFMA(a01, w0, acc1);
        acc2 = MFMA(a02, w0, acc2);
        acc3 = MFMA(a03, w0, acc3);
        a00=ldA(0,k2); a01=ldA(1,k2); a02=ldA(2,k2); a03=ldA(3,k2); w0=ldW(k2);
        acc0 = MFMA(a10, w1, acc0);
        acc1 = MFMA(a11, w1, acc1);
        acc2 = MFMA(a12, w1, acc2);
        acc3 = MFMA(a13, w1, acc3);
        a10=ldA(0,k3); a11=ldA(1,k3); a12=ldA(2,k3); a13=ldA(3,k3); w1=ldW(k3);
    }

    const float bn = bias[n0 + lr];
    #pragma unroll
    for (int v = 0; v < 4; ++v) {
        C[(size_t)( 0 + lg * 4 + v) * N + n0 + lr] = acc0[v] + bn;
        C[(size_t)(16 + lg * 4 + v) * N + n0 + lr] = acc1[v] + bn;
        C[(size_t)(32 + lg * 4 + v) * N + n0 + lr] = acc2[v] + bn;
        C[(size_t)(48 + lg * 4 + v) * N + n0 + lr] = acc3[v] + bn;
    }
}

// ---------------------------------------------------------------------------
// Row log-softmax over V=20000, out[b][step][v].
// ---------------------------------------------------------------------------
__global__ __launch_bounds__(256)
void log_softmax_k(const float* __restrict__ logits, float* __restrict__ out, int step)
{
    __shared__ float red[4];
    const int b   = blockIdx.x;
    const int tid = threadIdx.x;
    const float* row = logits + (size_t)b * Vv;

    float m = -1e30f;
    for (int v = tid; v < Vv; v += 256) m = fmaxf(m, row[v]);
    #pragma unroll
    for (int off = 32; off > 0; off >>= 1) m = fmaxf(m, __shfl_down(m, off, 64));
    if ((tid & 63) == 0) red[tid >> 6] = m;
    __syncthreads();
    m = fmaxf(fmaxf(red[0], red[1]), fmaxf(red[2], red[3]));
    __syncthreads();

    float s = 0.f;
    for (int v = tid; v < Vv; v += 256) s += expf(row[v] - m);
    #pragma unroll
    for (int off = 32; off > 0; off >>= 1) s += __shfl_down(s, off, 64);
    if ((tid & 63) == 0) red[tid >> 6] = s;
    __syncthreads();
    s = red[0] + red[1] + red[2] + red[3];
    const float lse = m + logf(s);

    float* orow = out + ((size_t)b * ML + step) * Vv;
    for (int v = tid; v < Vv; v += 256) orow[v] = row[v] - lse;
}

// ---------------------------------------------------------------------------
extern "C" void kernel_launch(void* const* d_in, const int* in_sizes, int n_in,
                              void* d_out, int out_size, void* d_ws, size_t ws_size,
                              hipStream_t stream)
{
    (void)in_sizes; (void)n_in; (void)out_size; (void)ws_size;
    const float* vid   = (const float*)d_in[0];
    const float* W_ih1 = (const float*)d_in[1];
    const float* W_hh1 = (const float*)d_in[2];
    const float* b_ih1 = (const float*)d_in[3];
    const float* b_hh1 = (const float*)d_in[4];
    const float* W_ih2 = (const float*)d_in[5];   // (3072,1536); cols 0..1023 used
    const float* W_hh2 = (const float*)d_in[6];
    const float* b_ih2 = (const float*)d_in[7];
    const float* b_hh2 = (const float*)d_in[8];
    const float* W_obj = (const float*)d_in[9];
    const float* b_obj = (const float*)d_in[10];
    const float* W_rel = (const float*)d_in[11];
    const float* b_rel = (const float*)d_in[12];
    float* out = (float*)d_out;

    // workspace carve-up
    char* p = (char*)d_ws;
    short* vid_bf   = (short*)p; p += (size_t)2048 * Dv * 2;        // 8.0 MB
    short* Wih1_bf  = (short*)p; p += (size_t)G3 * Dv * 2;          // 12.6 MB
    short* Whh1_bf  = (short*)p; p += (size_t)G3 * Hd * 2;          // 6.3 MB
    short* Wih2c_bf = (short*)p; p += (size_t)G3 * Hd * 2;          // 6.3 MB
    short* Whh2_bf  = (short*)p; p += (size_t)G3 * Hd * 2;          // 6.3 MB
    short* out1_bf  = (short*)p; p += (size_t)2048 * Hd * 2;        // 4.2 MB
    // --- zero zone (one memset): h double-buffers + barrier area ---
    char* zz = p;
    short* h1a = (short*)p; p += (size_t)64 * Hd * 2;
    short* h1b = (short*)p; p += (size_t)64 * Hd * 2;
    short* h2a = (short*)p; p += (size_t)64 * Hd * 2;
    short* h2b = (short*)p; p += (size_t)64 * Hd * 2;
    unsigned int* bar = (unsigned int*)p; p += 4096;                // 2 sets x 512 uints
    size_t zz_bytes = (size_t)(p - zz);
    float* xp1    = (float*)p; p += (size_t)2048 * G3 * 4;          // 25.2 MB (also xp2)
    float* xp2t   = (float*)p; p += (size_t)64 * G3 * 4;
    float* logits = (float*)p; p += (size_t)64 * Vv * 4;

    hipMemsetAsync(zz, 0, zz_bytes, stream);

    // conversions to bf16
    {
        long t8;
        t8 = (long)2048 * Dv / 8;
        cvt_f32_bf16<<<(t8 + 255) / 256, 256, 0, stream>>>(vid, vid_bf, t8, t8, 0, 0);
        t8 = (long)G3 * Dv / 8;
        cvt_f32_bf16<<<(t8 + 255) / 256, 256, 0, stream>>>(W_ih1, Wih1_bf, t8, t8, 0, 0);
        t8 = (long)G3 * Hd / 8;
        cvt_f32_bf16<<<(t8 + 255) / 256, 256, 0, stream>>>(W_hh1, Whh1_bf, t8, t8, 0, 0);
        cvt_f32_bf16<<<(t8 + 255) / 256, 256, 0, stream>>>(W_hh2, Whh2_bf, t8, t8, 0, 0);
        cvt_f32_bf16<<<(t8 + 255) / 256, 256, 0, stream>>>(W_ih2, Wih2c_bf, t8, Hd / 8,
                                                           Hd + 512, Hd);
    }

    // Phase 1: xp1 = vid @ W_ih1^T + b_ih1   (M=2048, N=3072, K=2048)
    gemm_mfma_128<<<dim3(G3 / 128, 2048 / 128), 256, 0, stream>>>(
        vid_bf, Dv, Wih1_bf, Dv, b_ih1, xp1, G3, Dv);

    // Phase 2: layer-1 scan, ONE launch (xp row = b*32 + s), writes out1
    gru_scan<<<64, 256, 0, stream>>>(xp1, Tt, 1, Whh1_bf, b_hh1,
                                     h1a, h1b, 0, out1_bf, Tt, bar + 0);
    int p1 = 0;  // (0 + 32) & 1 == 0 -> final h1 in h1a

    // Phase 3: xp2 = out1 @ W_ih2[:, :H]^T + b_ih2  (M=2048, N=3072, K=1024)
    float* xp2 = xp1;
    gemm_mfma_128<<<dim3(G3 / 128, 2048 / 128), 256, 0, stream>>>(
        out1_bf, Hd, Wih2c_bf, Hd, b_ih2, xp2, G3, Hd);

    // Phase 4: layer-2 scan, ONE launch (xp row = s*64 + b)
    gru_scan<<<64, 256, 0, stream>>>(xp2, 1, 64, Whh2_bf, b_hh2,
                                     h2a, h2b, 0, nullptr, Tt, bar + 512);
    int p2 = 0;

    // Phase 5: decode (gru_scan with T=1; barrier not executed)
    for (int i = 0; i < ML; ++i) {
        gru_scan<<<64, 256, 0, stream>>>(b_ih1, 0, 0, Whh1_bf, b_hh1,
                                         h1a, h1b, p1, nullptr, 1, bar);
        p1 ^= 1;
        short* h1cur = p1 ? h1b : h1a;
        skinny_mfma<false><<<G3 / 16, 64, 0, stream>>>(h1cur, (const void*)Wih2c_bf,
                                                       b_ih2, xp2t, G3);
        gru_scan<<<64, 256, 0, stream>>>(xp2t, 1, 0, Whh2_bf, b_hh2,
                                         h2a, h2b, p2, nullptr, 1, bar);
        p2 ^= 1;
        short* h2cur = p2 ? h2b : h2a;
        const float* Wo = (i == 1) ? W_rel : W_obj;
        const float* bo = (i == 1) ? b_rel : b_obj;
        skinny_mfma<true><<<Vv / 16, 64, 0, stream>>>(h2cur, (const void*)Wo, bo,
                                                      logits, Vv);
        log_softmax_k<<<64, 256, 0, stream>>>(logits, out, i);
    }
}